// Round 1
// baseline (404.698 us; speedup 1.0000x reference)
//
#include <hip/hip_runtime.h>

#define BB   64
#define KSEG 19
#define CC   384
#define HS   256
#define DD   256
#define KP1  20   // K + 1 (global feat row appended as all-ones weights)

// -------------------------------------------------------------------------
// Kernel 1: bilinear 256->16 downsample == mean of 2x2 at rows/cols {16i+7,16i+8}
// wds layout: [B*K, 16, 16] flat (matches k*256 + h*16 + w within a batch)
// -------------------------------------------------------------------------
__global__ __launch_bounds__(256) void k_downsample(const float* __restrict__ seg,
                                                    float* __restrict__ wds) {
    int idx = blockIdx.x * 256 + threadIdx.x;      // exactly B*K*256 threads
    int j  = idx & 15;
    int i  = (idx >> 4) & 15;
    int bk = idx >> 8;
    const float* S  = seg + (size_t)bk * (HS * HS);
    const float* p0 = S + (16 * i + 7) * HS + (16 * j + 7);
    const float* p1 = p0 + HS;
    wds[idx] = 0.25f * (p0[0] + p0[1] + p1[0] + p1[1]);
}

// -------------------------------------------------------------------------
// Kernel 2: all_feats[b,k,c] = (1/256) * sum_p wds_ext[b,k,p] * F[b,c,p]
// wds_ext row 19 == 1.0 (global mean). Per-b GEMM (20x256)@(256x384).
// Block = (c-chunk of 128, b). 256 threads: lane=c (64), group=k-quintet (4).
// -------------------------------------------------------------------------
__global__ __launch_bounds__(256) void k_feats(const float* __restrict__ F,
                                               const float* __restrict__ wds,
                                               float* __restrict__ feats) {
    __shared__ float wS[KP1][256];    // 20 KB
    __shared__ float Ft[128][65];     // 33.3 KB, +1 pad -> conflict-free
    const int t  = threadIdx.x;
    const int b  = blockIdx.y;
    const int c0 = blockIdx.x * 128;

    // stage wds for this b; k==19 row is all ones
    const float* wb = wds + (size_t)b * (KSEG * 256);
    for (int e = t; e < KP1 * 256; e += 256) {
        (&wS[0][0])[e] = (e < KSEG * 256) ? wb[e] : 1.0f;
    }

    const int c_lane = t & 63;
    const int kg     = t >> 6;
    const float* Fb  = F + ((size_t)b * CC + c0) * 256;
    float acc[5][2] = {};

    for (int pt = 0; pt < 4; ++pt) {
        __syncthreads();   // (iter 0: wS ready; iter>0: protect Ft from readers)
        // stage Ft[128 c][64 p] with coalesced float4 loads
        {
            int row  = t >> 1;
            int base = (t & 1) * 32;
            const float* src = Fb + row * 256 + pt * 64 + base;
#pragma unroll
            for (int q = 0; q < 8; ++q) {
                float4 v = *(const float4*)(src + q * 4);
                float* dst = &Ft[row][base + q * 4];
                dst[0] = v.x; dst[1] = v.y; dst[2] = v.z; dst[3] = v.w;
            }
        }
        __syncthreads();
        const int pb = pt * 64;
#pragma unroll 4
        for (int pp = 0; pp < 64; ++pp) {
            float f0 = Ft[c_lane][pp];
            float f1 = Ft[c_lane + 64][pp];
#pragma unroll
            for (int kk = 0; kk < 5; ++kk) {
                float wv = wS[kg * 5 + kk][pb + pp];   // wave-uniform broadcast
                acc[kk][0] += f0 * wv;
                acc[kk][1] += f1 * wv;
            }
        }
    }

    const float inv = 1.0f / 256.0f;
#pragma unroll
    for (int kk = 0; kk < 5; ++kk) {
        int k = kg * 5 + kk;
        float* o = feats + ((size_t)b * KP1 + k) * CC + c0 + c_lane;
        o[0]  = acc[kk][0] * inv;
        o[64] = acc[kk][1] * inv;
    }
}

// -------------------------------------------------------------------------
// Kernel 3: out[b,k,d] = relu(sum_c feats[b,k,c] * W[d,c] + bias[d])
// Per-b GEMM (20x384)@(384x256). Block = (d-chunk of 128, b).
// -------------------------------------------------------------------------
__global__ __launch_bounds__(256) void k_project(const float* __restrict__ feats,
                                                 const float* __restrict__ W,
                                                 const float* __restrict__ bias,
                                                 float* __restrict__ out) {
    __shared__ float fS[KP1][CC];     // 30.0 KB
    __shared__ float Wt[128][65];     // 33.3 KB  (total 64000 B <= 64 KB)
    const int t  = threadIdx.x;
    const int b  = blockIdx.y;
    const int d0 = blockIdx.x * 128;

    const float* fb = feats + (size_t)b * KP1 * CC;
    for (int e = t; e < KP1 * CC; e += 256) {
        (&fS[0][0])[e] = fb[e];
    }

    const int d_lane = t & 63;
    const int kg     = t >> 6;
    float acc[5][2] = {};

    for (int ct = 0; ct < 6; ++ct) {
        __syncthreads();
        {
            int row  = t >> 1;
            int base = (t & 1) * 32;
            const float* src = W + (size_t)(d0 + row) * CC + ct * 64 + base;
#pragma unroll
            for (int q = 0; q < 8; ++q) {
                float4 v = *(const float4*)(src + q * 4);
                float* dst = &Wt[row][base + q * 4];
                dst[0] = v.x; dst[1] = v.y; dst[2] = v.z; dst[3] = v.w;
            }
        }
        __syncthreads();
        const int cb = ct * 64;
#pragma unroll 4
        for (int cc = 0; cc < 64; ++cc) {
            float w0 = Wt[d_lane][cc];
            float w1 = Wt[d_lane + 64][cc];
#pragma unroll
            for (int kk = 0; kk < 5; ++kk) {
                float fv = fS[kg * 5 + kk][cb + cc];   // wave-uniform broadcast
                acc[kk][0] += w0 * fv;
                acc[kk][1] += w1 * fv;
            }
        }
    }

    float b0 = bias[d0 + d_lane];
    float b1 = bias[d0 + 64 + d_lane];
#pragma unroll
    for (int kk = 0; kk < 5; ++kk) {
        int k = kg * 5 + kk;
        float* o = out + ((size_t)b * KP1 + k) * DD + d0 + d_lane;
        float v0 = acc[kk][0] + b0;
        float v1 = acc[kk][1] + b1;
        o[0]  = v0 > 0.0f ? v0 : 0.0f;
        o[64] = v1 > 0.0f ? v1 : 0.0f;
    }
}

// -------------------------------------------------------------------------
extern "C" void kernel_launch(void* const* d_in, const int* in_sizes, int n_in,
                              void* d_out, int out_size, void* d_ws, size_t ws_size,
                              hipStream_t stream) {
    const float* F    = (const float*)d_in[0];   // [64,384,16,16]
    const float* seg  = (const float*)d_in[1];   // [64,19,256,256]
    const float* W    = (const float*)d_in[2];   // [256,384]
    const float* bias = (const float*)d_in[3];   // [256]
    float* out = (float*)d_out;                  // [64, 20*256] fp32

    float* wds   = (float*)d_ws;                 // B*K*256   = 311296 floats
    float* feats = wds + (size_t)BB * KSEG * 256; // B*20*384 = 491520 floats

    k_downsample<<<dim3((BB * KSEG * 256) / 256), dim3(256), 0, stream>>>(seg, wds);
    k_feats    <<<dim3(3, BB), dim3(256), 0, stream>>>(F, wds, feats);
    k_project  <<<dim3(2, BB), dim3(256), 0, stream>>>(feats, W, bias, out);
}

// Round 2
// 391.460 us; speedup vs baseline: 1.0338x; 1.0338x over previous
//
#include <hip/hip_runtime.h>

#define BB   64
#define KSEG 19
#define CC   384
#define HS   256
#define DD   256
#define KP1  20   // K + 1 (global feat row appended as all-ones weights)

// -------------------------------------------------------------------------
// Kernel 1: bilinear 256->16 == mean of 2x2 at rows/cols {16i+7,16i+8}.
// One block per (b,k) image: stage the 32 needed rows (32 KB) coalesced,
// then pick from LDS. wds layout: [B*K, 16, 16] flat.
// -------------------------------------------------------------------------
__global__ __launch_bounds__(256) void k_downsample(const float* __restrict__ seg,
                                                    float* __restrict__ wds) {
    __shared__ __align__(16) float rows[32][257];   // +1 pad
    const int t  = threadIdx.x;
    const int bk = blockIdx.x;
    const float* S = seg + (size_t)bk * (HS * HS);

    // stage rows {16i+7, 16i+8} for i=0..15: 32 rows x 1 KB, float4-coalesced
#pragma unroll
    for (int it = 0; it < 8; ++it) {
        int f   = it * 256 + t;       // float4 index, 0..2047
        int r   = f >> 6;             // local row 0..31 (one wave == one row)
        int c4  = f & 63;
        int grow = 16 * (r >> 1) + 7 + (r & 1);
        float4 v = *(const float4*)(S + grow * HS + c4 * 4);
        float* dst = &rows[r][c4 * 4];
        dst[0] = v.x; dst[1] = v.y; dst[2] = v.z; dst[3] = v.w;
    }
    __syncthreads();

    int j = t & 15, i = t >> 4;
    float s = rows[2*i    ][16*j + 7] + rows[2*i    ][16*j + 8]
            + rows[2*i + 1][16*j + 7] + rows[2*i + 1][16*j + 8];
    wds[bk * 256 + t] = 0.25f * s;    // coalesced 1 KB store
}

// -------------------------------------------------------------------------
// Kernel 2: all_feats[b,k,c] = (1/256) * sum_p wds_ext[b,k,p] * F[b,c,p]
// Grid (6, B): c-chunk of 64. 256 threads = 64 c-lanes x 4 k-groups(5).
// wS reads are same-address float4 broadcasts (b128, conflict-free).
// -------------------------------------------------------------------------
__global__ __launch_bounds__(256) void k_feats(const float* __restrict__ F,
                                               const float* __restrict__ wds,
                                               float* __restrict__ feats) {
    __shared__ __align__(16) float wS[KP1][256];   // 20 KB
    __shared__ __align__(16) float Ft[64][65];     // 16.6 KB, pad -> 2-way (free)
    const int t  = threadIdx.x;
    const int b  = blockIdx.y;
    const int c0 = blockIdx.x * 64;

    const float* wb = wds + (size_t)b * (KSEG * 256);
    for (int e = t; e < KP1 * 256; e += 256)
        (&wS[0][0])[e] = (e < KSEG * 256) ? wb[e] : 1.0f;

    const int c_lane = t & 63;
    const int kg     = t >> 6;
    const float* Fb  = F + ((size_t)b * CC + c0) * 256;
    float acc[5] = {};

    for (int pt = 0; pt < 4; ++pt) {
        __syncthreads();
        // stage Ft[64 c][64 p]: 1024 float4s, 4 per thread
#pragma unroll
        for (int it = 0; it < 4; ++it) {
            int f  = it * 256 + t;
            int r  = f >> 4;
            int c4 = f & 15;
            float4 v = *(const float4*)(Fb + r * 256 + pt * 64 + c4 * 4);
            float* dst = &Ft[r][c4 * 4];
            dst[0] = v.x; dst[1] = v.y; dst[2] = v.z; dst[3] = v.w;
        }
        __syncthreads();
#pragma unroll 4
        for (int q4 = 0; q4 < 16; ++q4) {
            const float* fp = &Ft[c_lane][q4 * 4];
            float f0 = fp[0], f1 = fp[1], f2 = fp[2], f3 = fp[3];
#pragma unroll
            for (int kk = 0; kk < 5; ++kk) {
                float4 wv = *(const float4*)&wS[kg * 5 + kk][pt * 64 + q4 * 4];
                acc[kk] += f0 * wv.x + f1 * wv.y + f2 * wv.z + f3 * wv.w;
            }
        }
    }

    const float inv = 1.0f / 256.0f;
#pragma unroll
    for (int kk = 0; kk < 5; ++kk) {
        int k = kg * 5 + kk;
        feats[((size_t)b * KP1 + k) * CC + c0 + c_lane] = acc[kk] * inv;
    }
}

// -------------------------------------------------------------------------
// Kernel 3: out[b,k,d] = relu(sum_c feats[b,k,c] * W[d,c] + bias[d])
// Grid (4, B): d-chunk of 64. fS reads are float4 broadcasts.
// -------------------------------------------------------------------------
__global__ __launch_bounds__(256) void k_project(const float* __restrict__ feats,
                                                 const float* __restrict__ W,
                                                 const float* __restrict__ bias,
                                                 float* __restrict__ out) {
    __shared__ __align__(16) float fS[KP1][CC];    // 30 KB
    __shared__ __align__(16) float Wt[64][65];     // 16.6 KB
    const int t  = threadIdx.x;
    const int b  = blockIdx.y;
    const int d0 = blockIdx.x * 64;

    // stage feats[b]: 20*384 = 7680 floats = 1920 float4s
    const float* fb = feats + (size_t)b * KP1 * CC;
#pragma unroll
    for (int it = 0; it < 8; ++it) {
        int f = it * 256 + t;
        if (f < (KP1 * CC) / 4) {
            float4 v = *(const float4*)(fb + f * 4);
            float* dst = &(&fS[0][0])[f * 4];
            dst[0] = v.x; dst[1] = v.y; dst[2] = v.z; dst[3] = v.w;
        }
    }

    const int d_lane = t & 63;
    const int kg     = t >> 6;
    float acc[5] = {};

    for (int ct = 0; ct < 6; ++ct) {
        __syncthreads();
        // stage Wt[64 d][64 c]
#pragma unroll
        for (int it = 0; it < 4; ++it) {
            int f  = it * 256 + t;
            int r  = f >> 4;
            int c4 = f & 15;
            float4 v = *(const float4*)(W + (size_t)(d0 + r) * CC + ct * 64 + c4 * 4);
            float* dst = &Wt[r][c4 * 4];
            dst[0] = v.x; dst[1] = v.y; dst[2] = v.z; dst[3] = v.w;
        }
        __syncthreads();
#pragma unroll 4
        for (int q4 = 0; q4 < 16; ++q4) {
            const float* wp = &Wt[d_lane][q4 * 4];
            float w0 = wp[0], w1 = wp[1], w2 = wp[2], w3 = wp[3];
#pragma unroll
            for (int kk = 0; kk < 5; ++kk) {
                float4 fv = *(const float4*)&fS[kg * 5 + kk][ct * 64 + q4 * 4];
                acc[kk] += w0 * fv.x + w1 * fv.y + w2 * fv.z + w3 * fv.w;
            }
        }
    }

    float bv = bias[d0 + d_lane];
#pragma unroll
    for (int kk = 0; kk < 5; ++kk) {
        int k = kg * 5 + kk;
        float v = acc[kk] + bv;
        out[((size_t)b * KP1 + k) * DD + d0 + d_lane] = v > 0.0f ? v : 0.0f;
    }
}

// -------------------------------------------------------------------------
extern "C" void kernel_launch(void* const* d_in, const int* in_sizes, int n_in,
                              void* d_out, int out_size, void* d_ws, size_t ws_size,
                              hipStream_t stream) {
    const float* F    = (const float*)d_in[0];   // [64,384,16,16]
    const float* seg  = (const float*)d_in[1];   // [64,19,256,256]
    const float* W    = (const float*)d_in[2];   // [256,384]
    const float* bias = (const float*)d_in[3];   // [256]
    float* out = (float*)d_out;                  // [64, 20*256] fp32

    float* wds   = (float*)d_ws;                   // B*K*256   = 311296 floats
    float* feats = wds + (size_t)BB * KSEG * 256;  // B*20*384  = 491520 floats

    k_downsample<<<dim3(BB * KSEG), dim3(256), 0, stream>>>(seg, wds);
    k_feats    <<<dim3(6, BB), dim3(256), 0, stream>>>(F, wds, feats);
    k_project  <<<dim3(4, BB), dim3(256), 0, stream>>>(feats, W, bias, out);
}